// Round 2
// baseline (1812.242 us; speedup 1.0000x reference)
//
#include <hip/hip_runtime.h>
#include <hip/hip_bf16.h>

// Problem constants (fixed by the reference):
//   x: [4,2048,4096] fp32 -> M=8192 tokens, K=4096
//   ternary_weight: [16384,4096] int32 in {-1,0,1} -> N=16384
//   out: [8192,16384] fp32
#define M_TOK 8192
#define N_OUT 16384
#define K_IN  4096

typedef int v4i __attribute__((ext_vector_type(4)));

// ---------------------------------------------------------------------------
// Kernel 1: weight int32 -> int8 pack. 16 elements per thread, int4-out.
// ---------------------------------------------------------------------------
__device__ __forceinline__ int pack4(int4 v) {
    return (v.x & 255) | ((v.y & 255) << 8) | ((v.z & 255) << 16) | (v.w << 24);
}

__global__ __launch_bounds__(256) void cvt_w_kernel(const int* __restrict__ w,
                                                    int4* __restrict__ w8) {
    size_t i = (size_t)blockIdx.x * blockDim.x + threadIdx.x;  // over 4194304
    const int4* wi = (const int4*)w + i * 4;
    int4 o;
    o.x = pack4(wi[0]);
    o.y = pack4(wi[1]);
    o.z = pack4(wi[2]);
    o.w = pack4(wi[3]);
    w8[i] = o;
}

// ---------------------------------------------------------------------------
// Kernel 2: per-token dynamic int8 quantization.
// One block (256 threads) per token row of 4096 floats; 16 elems/thread,
// contiguous, one int4 (16x int8) store per thread.
// act_scale = max(max|x|, 1e-5) / 127 ; q = clip(rint(x/act_scale), -128, 127)
// rintf == round-half-even == np.round; IEEE fp32 division matches numpy.
// ---------------------------------------------------------------------------
__global__ __launch_bounds__(256) void quant_kernel(const float* __restrict__ x,
                                                    int4* __restrict__ qx,
                                                    float* __restrict__ scales) {
    int token = blockIdx.x;
    const float4* xr = (const float4*)(x + (size_t)token * K_IN);
    int t = threadIdx.x;

    float4 v[4];
    float m = 0.f;
#pragma unroll
    for (int u = 0; u < 4; ++u) {
        v[u] = xr[t * 4 + u];
        m = fmaxf(m, fmaxf(fmaxf(fabsf(v[u].x), fabsf(v[u].y)),
                           fmaxf(fabsf(v[u].z), fabsf(v[u].w))));
    }
    // wave (64-lane) max reduce
#pragma unroll
    for (int off = 32; off > 0; off >>= 1) m = fmaxf(m, __shfl_xor(m, off));

    __shared__ float wmax[4];
    int lane = t & 63, w = t >> 6;
    if (lane == 0) wmax[w] = m;
    __syncthreads();
    float bm = fmaxf(fmaxf(wmax[0], wmax[1]), fmaxf(wmax[2], wmax[3]));
    float scale = fmaxf(bm, 1e-5f) / 127.0f;
    if (t == 0) scales[token] = scale;

    int4 q;
    int* qp = (int*)&q;
#pragma unroll
    for (int u = 0; u < 4; ++u) {
        float4 f = v[u];
        int4 r;
        r.x = (int)fminf(fmaxf(rintf(f.x / scale), -128.f), 127.f);
        r.y = (int)fminf(fmaxf(rintf(f.y / scale), -128.f), 127.f);
        r.z = (int)fminf(fmaxf(rintf(f.z / scale), -128.f), 127.f);
        r.w = (int)fminf(fmaxf(rintf(f.w / scale), -128.f), 127.f);
        qp[u] = pack4(r);
    }
    qx[(size_t)token * 256 + t] = q;
}

// ---------------------------------------------------------------------------
// Kernel 3: int8 GEMM  out[m,n] = i32dot(qx[m,:], w8[n,:]) * scales[m]*wsc + bias[n]
// 128x128 tile, BK=64 (bytes), 256 threads = 4 waves in 2x2, each wave 64x64
// via 4x4 grid of mfma_i32_16x16x64_i8.
//
// DOUBLE-BUFFERED K-loop, ONE barrier per iteration:
//   barrier (vmcnt(0) drains tile-k loads; lgkmcnt drains prev ds_reads)
//   -> issue tile k+1 loads into other buffer
//   -> ds_read tile k, 16 MFMAs
// The prefetch has a full compute phase (~300 cyc/wave x ~11 waves/CU) to
// land before the next barrier's vmcnt(0) — vs R1's zero-distance drain.
//
// LDS layout per buffer: [kchunk(4)][row(128)][16B] so the global_load_lds
// staging (wave-uniform base + lane*16) and ds_read_b128 fragment reads
// (16 lanes -> 256 contiguous bytes, 2-way alias = free) both work.
// A-frag: row = lane&15 (+16i), k = (lane>>4)*16 .. +16   (16 contiguous B)
// B-frag: col = lane&15 (+16j), same k split.
// C/D: col = lane&15, row = (lane>>4)*4 + reg   [m89, dtype-independent]
// ---------------------------------------------------------------------------
#define TM 128
#define TN 128
#define TK 64
#define NITER (K_IN / TK)

__global__ __launch_bounds__(256) void gemm_kernel(
    const signed char* __restrict__ A,   // [M_TOK][K_IN] qx
    const signed char* __restrict__ B,   // [N_OUT][K_IN] w8
    const float* __restrict__ scales,    // [M_TOK]
    const float* __restrict__ wscale,    // [1]
    const float* __restrict__ bias,      // [N_OUT]
    float* __restrict__ out)             // [M_TOK][N_OUT]
{
    __shared__ __align__(16) signed char smA[2][4][TM][16];  // 16 KB
    __shared__ __align__(16) signed char smB[2][4][TN][16];  // 16 KB

    const int t = threadIdx.x;
    const int lane = t & 63;
    const int w = t >> 6;
    const int wm = w >> 1;   // 0..1
    const int wn = w & 1;    // 0..1

    // Grouped-M swizzle: consecutive blocks share the same B tile (n), walk m.
    const int num_pid_m = M_TOK / TM;   // 64
    const int num_pid_n = N_OUT / TN;   // 128
    const int GROUP = 16;
    int bid = blockIdx.y * gridDim.x + blockIdx.x;
    int npg = GROUP * num_pid_n;
    int group_id = bid / npg;
    int first_m = group_id * GROUP;
    int gsm = min(num_pid_m - first_m, GROUP);
    int pid_m = first_m + (bid % gsm);
    int pid_n = (bid % npg) / gsm;

    const int m0 = pid_m * TM;
    const int n0 = pid_n * TN;

    // Staging: chunk s (0..511) -> LDS bytes [s*16, s*16+16),
    // global (row = s&127, kchunk = s>>7). s_lo = t, s_hi = t + 256.
    const signed char* ga_lo = A + (size_t)(m0 + (t & 127)) * K_IN + (t >> 7) * 16;
    const signed char* ga_hi = ga_lo + 32;  // kchunk += 2
    const signed char* gb_lo = B + (size_t)(n0 + (t & 127)) * K_IN + (t >> 7) * 16;
    const signed char* gb_hi = gb_lo + 32;

    // wave-uniform LDS bases (HW adds lane*16); + buf*8192 selects buffer
    signed char* const sA = &smA[0][0][0][0];
    signed char* const sB = &smB[0][0][0][0];

    v4i acc[4][4] = {};

    const int r = lane & 15;
    const int g = lane >> 4;

    // prologue: tile 0 into buffer 0
    {
        __builtin_amdgcn_global_load_lds(
            (const __attribute__((address_space(1))) void*)ga_lo,
            (__attribute__((address_space(3))) void*)(sA + w * 1024), 16, 0, 0);
        __builtin_amdgcn_global_load_lds(
            (const __attribute__((address_space(1))) void*)ga_hi,
            (__attribute__((address_space(3))) void*)(sA + 4096 + w * 1024), 16, 0, 0);
        __builtin_amdgcn_global_load_lds(
            (const __attribute__((address_space(1))) void*)gb_lo,
            (__attribute__((address_space(3))) void*)(sB + w * 1024), 16, 0, 0);
        __builtin_amdgcn_global_load_lds(
            (const __attribute__((address_space(1))) void*)gb_hi,
            (__attribute__((address_space(3))) void*)(sB + 4096 + w * 1024), 16, 0, 0);
    }

    for (int it = 0; it < NITER; ++it) {
        const int cur = it & 1;
        __syncthreads();  // vmcnt(0): buf[cur] loads landed; prev reads of buf[cur^1] done

        if (it + 1 < NITER) {
            const int nb = (cur ^ 1) * 8192;
            const int koff = (it + 1) * TK;
            __builtin_amdgcn_global_load_lds(
                (const __attribute__((address_space(1))) void*)(ga_lo + koff),
                (__attribute__((address_space(3))) void*)(sA + nb + w * 1024), 16, 0, 0);
            __builtin_amdgcn_global_load_lds(
                (const __attribute__((address_space(1))) void*)(ga_hi + koff),
                (__attribute__((address_space(3))) void*)(sA + nb + 4096 + w * 1024), 16, 0, 0);
            __builtin_amdgcn_global_load_lds(
                (const __attribute__((address_space(1))) void*)(gb_lo + koff),
                (__attribute__((address_space(3))) void*)(sB + nb + w * 1024), 16, 0, 0);
            __builtin_amdgcn_global_load_lds(
                (const __attribute__((address_space(1))) void*)(gb_hi + koff),
                (__attribute__((address_space(3))) void*)(sB + nb + 4096 + w * 1024), 16, 0, 0);
        }

        v4i a[4], b[4];
#pragma unroll
        for (int i = 0; i < 4; ++i)
            a[i] = *(const v4i*)&smA[cur][g][wm * 64 + i * 16 + r][0];
#pragma unroll
        for (int j = 0; j < 4; ++j)
            b[j] = *(const v4i*)&smB[cur][g][wn * 64 + j * 16 + r][0];

#pragma unroll
        for (int i = 0; i < 4; ++i)
#pragma unroll
            for (int j = 0; j < 4; ++j)
                acc[i][j] = __builtin_amdgcn_mfma_i32_16x16x64_i8(a[i], b[j], acc[i][j], 0, 0, 0);
    }

    // Epilogue: out = acc * scales[m]*wsc + bias[n]
    const float wsc = wscale[0];
    const int col0 = n0 + wn * 64 + (lane & 15);
    const int rbase = (lane >> 4) * 4;
#pragma unroll
    for (int i = 0; i < 4; ++i) {
        const int rowA = m0 + wm * 64 + i * 16 + rbase;
#pragma unroll
        for (int rr = 0; rr < 4; ++rr) {
            const float as_ = scales[rowA + rr] * wsc;
            float* orow = out + (size_t)(rowA + rr) * N_OUT;
#pragma unroll
            for (int j = 0; j < 4; ++j) {
                const int c = col0 + j * 16;
                orow[c] = (float)acc[i][j][rr] * as_ + bias[c];
            }
        }
    }
}

// ---------------------------------------------------------------------------
extern "C" void kernel_launch(void* const* d_in, const int* in_sizes, int n_in,
                              void* d_out, int out_size, void* d_ws, size_t ws_size,
                              hipStream_t stream) {
    const float* x      = (const float*)d_in[0];   // [8192*4096] fp32
    const int*   tw     = (const int*)d_in[1];     // [16384*4096] int32
    const float* wscale = (const float*)d_in[2];   // [1]
    const float* bias   = (const float*)d_in[3];   // [16384]
    float* out = (float*)d_out;                    // [8192*16384] fp32

    // workspace layout: qx (32MB) | w8 (64MB) | scales (32KB)
    signed char* qx = (signed char*)d_ws;
    signed char* w8 = qx + (size_t)M_TOK * K_IN;
    float* scales = (float*)(w8 + (size_t)N_OUT * K_IN);

    // 1) weight pack: 67108864 elems / 16 per thread / 256 = 16384 blocks
    cvt_w_kernel<<<16384, 256, 0, stream>>>(tw, (int4*)w8);
    // 2) per-token quantization: one block per token
    quant_kernel<<<M_TOK, 256, 0, stream>>>(x, (int4*)qx, scales);
    // 3) int8 GEMM: grid (N/128, M/128) = (128, 64)
    dim3 grid(N_OUT / TN, M_TOK / TM);
    gemm_kernel<<<grid, 256, 0, stream>>>(qx, w8, scales, wscale, bias, out);
}